// Round 1
// baseline (186.074 us; speedup 1.0000x reference)
//
#include <hip/hip_runtime.h>

#define NN 1200
#define NE 719400
#define SDIM 4800

static __device__ __constant__ int SMAT[16] = {0,1,2,3,1,4,5,6,2,5,7,8,3,6,8,9};

__device__ __forceinline__ float lk(float v) { return v >= 0.f ? v : 0.1f * v; }

// ---------------- init ----------------
__global__ void k_init(float* cs) {
    int t = threadIdx.x;
    if (t < 128) cs[t] = 0.f;
}

// ---------------- GCN stage 1: t1 = x6 @ Wg1 (1200x32), colsum ----------------
__global__ __launch_bounds__(256) void k_t1(const float* __restrict__ x,
                                            const float* __restrict__ Wg1,
                                            float* __restrict__ t1,
                                            float* __restrict__ cs1) {
    int T = blockIdx.x * 256 + threadIdx.x;   // 38*256 = 9728 = 304*32
    int c = T & 31, rs = T >> 5;              // rs 0..303
    float w[6];
#pragma unroll
    for (int k = 0; k < 6; k++) w[k] = Wg1[k * 32 + c];
    float loc = 0.f;
    for (int r = rs; r < NN; r += 304) {
        float acc = 0.f;
#pragma unroll
        for (int k = 0; k < 6; k++) acc = fmaf(x[r * 16 + k], w[k], acc);
        t1[r * 32 + c] = acc;
        loc += acc;
    }
    atomicAdd(&cs1[c], loc);
}

// ---------------- GCN stage 2: h1 = act(t1), t2 = h1 @ Wg2 (1200x32) ----------------
__global__ __launch_bounds__(256) void k_t2(const float* __restrict__ t1,
                                            const float* __restrict__ cs1,
                                            const float* __restrict__ bg1,
                                            const float* __restrict__ Wg2,
                                            float* __restrict__ t2,
                                            float* __restrict__ cs2) {
    int T = blockIdx.x * 256 + threadIdx.x;
    int c = T & 31, rs = T >> 5;
    const float inv = 1.0f / 1199.0f;
    float p[32], w[32];
#pragma unroll
    for (int k = 0; k < 32; k++) {
        p[k] = fmaf(cs1[k], inv, bg1[k]);
        w[k] = Wg2[k * 32 + c];
    }
    float loc = 0.f;
    for (int r = rs; r < NN; r += 304) {
        float acc = 0.f;
#pragma unroll
        for (int k = 0; k < 32; k++) {
            float h = lk(fmaf(-t1[r * 32 + k], inv, p[k]));
            acc = fmaf(h, w[k], acc);
        }
        t2[r * 32 + c] = acc;
        loc += acc;
    }
    atomicAdd(&cs2[c], loc);
}

// ---------------- GCN stage 3: h2 = act(t2), t3 = h2 @ Wg3 (1200x64) ----------------
__global__ __launch_bounds__(256) void k_t3(const float* __restrict__ t2,
                                            const float* __restrict__ cs2,
                                            const float* __restrict__ bg2,
                                            const float* __restrict__ Wg3,
                                            float* __restrict__ t3,
                                            float* __restrict__ cs3) {
    int T = blockIdx.x * 256 + threadIdx.x;   // 9728 = 152*64
    int c = T & 63, rs = T >> 6;              // rs 0..151
    const float inv = 1.0f / 1199.0f;
    float p[32], w[32];
#pragma unroll
    for (int k = 0; k < 32; k++) {
        p[k] = fmaf(cs2[k], inv, bg2[k]);
        w[k] = Wg3[k * 64 + c];
    }
    float loc = 0.f;
    for (int r = rs; r < NN; r += 152) {
        float acc = 0.f;
#pragma unroll
        for (int k = 0; k < 32; k++) {
            float h = lk(fmaf(-t2[r * 32 + k], inv, p[k]));
            acc = fmaf(h, w[k], acc);
        }
        t3[r * 64 + c] = acc;
        loc += acc;
    }
    atomicAdd(&cs3[c], loc);
}

// ---------------- shared 2x8 register-tile GEMM from LDS ----------------
__device__ __forceinline__ void gemm2x8(const float A[64][65], const float* W,
                                        int rg, int cg, float acc[2][8]) {
#pragma unroll 8
    for (int k = 0; k < 64; k++) {
        float a0 = A[rg * 2 + 0][k];
        float a1 = A[rg * 2 + 1][k];
        float4 b0 = *(const float4*)&W[k * 64 + cg * 8];
        float4 b1 = *(const float4*)&W[k * 64 + cg * 8 + 4];
        acc[0][0] = fmaf(a0, b0.x, acc[0][0]); acc[0][1] = fmaf(a0, b0.y, acc[0][1]);
        acc[0][2] = fmaf(a0, b0.z, acc[0][2]); acc[0][3] = fmaf(a0, b0.w, acc[0][3]);
        acc[0][4] = fmaf(a0, b1.x, acc[0][4]); acc[0][5] = fmaf(a0, b1.y, acc[0][5]);
        acc[0][6] = fmaf(a0, b1.z, acc[0][6]); acc[0][7] = fmaf(a0, b1.w, acc[0][7]);
        acc[1][0] = fmaf(a1, b0.x, acc[1][0]); acc[1][1] = fmaf(a1, b0.y, acc[1][1]);
        acc[1][2] = fmaf(a1, b0.z, acc[1][2]); acc[1][3] = fmaf(a1, b0.w, acc[1][3]);
        acc[1][4] = fmaf(a1, b1.x, acc[1][4]); acc[1][5] = fmaf(a1, b1.y, acc[1][5]);
        acc[1][6] = fmaf(a1, b1.z, acc[1][6]); acc[1][7] = fmaf(a1, b1.w, acc[1][7]);
    }
}

// ---------------- node kernel: h3, g = h3@We1, vd = mlp3(h3), diag blocks ----------------
__global__ __launch_bounds__(256) void k_node(
    const float* __restrict__ t3, const float* __restrict__ cs3,
    const float* __restrict__ bg3,
    const float* __restrict__ We1,
    const float* __restrict__ Wn1, const float* __restrict__ bn1,
    const float* __restrict__ Wn2, const float* __restrict__ bn2,
    const float* __restrict__ Wn3, const float* __restrict__ bn3,
    float* __restrict__ h_out, float* __restrict__ g_out,
    float* __restrict__ S) {
    __shared__ float H[64][65];
    __shared__ float N1s[64][65];
    __shared__ float WA[4096];
    __shared__ float WB[4096];
    __shared__ float WC[4096];
    __shared__ float WD[640];
    __shared__ float VD[64][12];
    __shared__ float sbn1[64], sbn2[64], sbn3[16];

    const int tid = threadIdx.x;
    const int r0 = blockIdx.x * 64;
    const float inv = 1.0f / 1199.0f;

    for (int t = tid; t < 1024; t += 256) {
        ((float4*)WA)[t] = ((const float4*)We1)[t];
        ((float4*)WB)[t] = ((const float4*)Wn1)[t];
        ((float4*)WC)[t] = ((const float4*)Wn2)[t];
    }
    for (int t = tid; t < 640; t += 256) WD[t] = Wn3[t];
    if (tid < 64) { sbn1[tid] = bn1[tid]; sbn2[tid] = bn2[tid]; }
    if (tid < 10) sbn3[tid] = bn3[tid];

    // h3 rows -> LDS + global h output
    for (int t = tid; t < 4096; t += 256) {
        int i = t >> 6, c = t & 63;
        int row = r0 + i;
        float v = 0.f;
        if (row < NN) {
            v = fmaf(cs3[c] - t3[row * 64 + c], inv, bg3[c]);
            h_out[row * 64 + c] = v;
        }
        H[i][c] = v;
    }
    __syncthreads();

    const int rg = tid >> 3;  // 0..31
    const int cg = tid & 7;   // 0..7

    // g = h3 @ We1 (no bias, no act)
    {
        float acc[2][8] = {};
        gemm2x8(H, WA, rg, cg, acc);
#pragma unroll
        for (int m = 0; m < 2; m++) {
            int row = r0 + rg * 2 + m;
            if (row < NN) {
                *(float4*)&g_out[row * 64 + cg * 8]     = make_float4(acc[m][0], acc[m][1], acc[m][2], acc[m][3]);
                *(float4*)&g_out[row * 64 + cg * 8 + 4] = make_float4(acc[m][4], acc[m][5], acc[m][6], acc[m][7]);
            }
        }
    }
    // n1 = act(h3 @ Wn1 + bn1)
    {
        float acc[2][8] = {};
        gemm2x8(H, WB, rg, cg, acc);
#pragma unroll
        for (int m = 0; m < 2; m++)
#pragma unroll
            for (int q = 0; q < 8; q++)
                N1s[rg * 2 + m][cg * 8 + q] = lk(acc[m][q] + sbn1[cg * 8 + q]);
    }
    __syncthreads();
    // n2 = act(n1 @ Wn2 + bn2) -> overwrite H (all H reads completed before prior sync)
    {
        float acc[2][8] = {};
        gemm2x8(N1s, WC, rg, cg, acc);
#pragma unroll
        for (int m = 0; m < 2; m++)
#pragma unroll
            for (int q = 0; q < 8; q++)
                H[rg * 2 + m][cg * 8 + q] = lk(acc[m][q] + sbn2[cg * 8 + q]);
    }
    __syncthreads();
    // vd = n2 @ Wn3 + bn3  (64x10)
    for (int t = tid; t < 640; t += 256) {
        int r = t / 10, c = t % 10;
        float acc = sbn3[c];
        for (int k = 0; k < 64; k++) acc = fmaf(H[r][k], WD[k * 10 + c], acc);
        VD[r][c] = acc;
    }
    __syncthreads();
    // diagonal Vsym blocks
    {
        int r = tid >> 2, a = tid & 3;  // 64 x 4
        int row = r0 + r;
        if (row < NN) {
            float4 v = make_float4(VD[r][SMAT[a * 4 + 0]], VD[r][SMAT[a * 4 + 1]],
                                   VD[r][SMAT[a * 4 + 2]], VD[r][SMAT[a * 4 + 3]]);
            *(float4*)&S[(4 * row + a) * SDIM + 4 * row] = v;
        }
    }
}

// ---------------- edge kernel: 128 edges per WG ----------------
__global__ __launch_bounds__(256) void k_edge(const int* __restrict__ ud,
                                              const float* __restrict__ g,
                                              const float* __restrict__ be1,
                                              const float* __restrict__ We2,
                                              const float* __restrict__ be2,
                                              const float* __restrict__ We3,
                                              const float* __restrict__ be3,
                                              float* __restrict__ S) {
    __shared__ float U[128][65];
    __shared__ float W2[4096];
    __shared__ float W3[1024];
    __shared__ float ED[128][16];
    __shared__ float b1s[64], b2s[64], b3s[16];
    __shared__ int II[128], JJ[128];

    const int tid = threadIdx.x;
    const int base = blockIdx.x * 128;

    for (int t = tid; t < 1024; t += 256) ((float4*)W2)[t] = ((const float4*)We2)[t];
    for (int t = tid; t < 256; t += 256)  ((float4*)W3)[t] = ((const float4*)We3)[t];
    if (tid < 64) { b1s[tid] = be1[tid]; b2s[tid] = be2[tid]; }
    if (tid < 16) b3s[tid] = be3[tid];
    if (tid < 128) {
        int e = base + tid;
        int2 ij = make_int2(0, 0);
        if (e < NE) ij = ((const int2*)ud)[e];
        II[tid] = ij.x; JJ[tid] = ij.y;
    }
    __syncthreads();

    // phase 1: U = act(g[i] + g[j] + be1)
    {
        int r = tid >> 1, half = tid & 1;
        int i = II[r], j = JJ[r];
        const float4* gi = (const float4*)&g[i * 64 + half * 32];
        const float4* gj = (const float4*)&g[j * 64 + half * 32];
#pragma unroll
        for (int q = 0; q < 8; q++) {
            float4 a = gi[q], b = gj[q];
            int c0 = half * 32 + q * 4;
            U[r][c0 + 0] = lk(a.x + b.x + b1s[c0 + 0]);
            U[r][c0 + 1] = lk(a.y + b.y + b1s[c0 + 1]);
            U[r][c0 + 2] = lk(a.z + b.z + b1s[c0 + 2]);
            U[r][c0 + 3] = lk(a.w + b.w + b1s[c0 + 3]);
        }
    }
    __syncthreads();

    // phase 2: V = act(U @ We2 + be2), 4 rows x 8 cols per thread
    const int rg = tid >> 3;  // 0..31 -> rows rg*4..+3
    const int cg = tid & 7;   // cols cg*8..+7
    float acc[4][8] = {};
#pragma unroll 4
    for (int k = 0; k < 64; k++) {
        float a0 = U[rg * 4 + 0][k];
        float a1 = U[rg * 4 + 1][k];
        float a2 = U[rg * 4 + 2][k];
        float a3 = U[rg * 4 + 3][k];
        float4 b0 = *(const float4*)&W2[k * 64 + cg * 8];
        float4 b1 = *(const float4*)&W2[k * 64 + cg * 8 + 4];
        acc[0][0] = fmaf(a0, b0.x, acc[0][0]); acc[0][1] = fmaf(a0, b0.y, acc[0][1]);
        acc[0][2] = fmaf(a0, b0.z, acc[0][2]); acc[0][3] = fmaf(a0, b0.w, acc[0][3]);
        acc[0][4] = fmaf(a0, b1.x, acc[0][4]); acc[0][5] = fmaf(a0, b1.y, acc[0][5]);
        acc[0][6] = fmaf(a0, b1.z, acc[0][6]); acc[0][7] = fmaf(a0, b1.w, acc[0][7]);
        acc[1][0] = fmaf(a1, b0.x, acc[1][0]); acc[1][1] = fmaf(a1, b0.y, acc[1][1]);
        acc[1][2] = fmaf(a1, b0.z, acc[1][2]); acc[1][3] = fmaf(a1, b0.w, acc[1][3]);
        acc[1][4] = fmaf(a1, b1.x, acc[1][4]); acc[1][5] = fmaf(a1, b1.y, acc[1][5]);
        acc[1][6] = fmaf(a1, b1.z, acc[1][6]); acc[1][7] = fmaf(a1, b1.w, acc[1][7]);
        acc[2][0] = fmaf(a2, b0.x, acc[2][0]); acc[2][1] = fmaf(a2, b0.y, acc[2][1]);
        acc[2][2] = fmaf(a2, b0.z, acc[2][2]); acc[2][3] = fmaf(a2, b0.w, acc[2][3]);
        acc[2][4] = fmaf(a2, b1.x, acc[2][4]); acc[2][5] = fmaf(a2, b1.y, acc[2][5]);
        acc[2][6] = fmaf(a2, b1.z, acc[2][6]); acc[2][7] = fmaf(a2, b1.w, acc[2][7]);
        acc[3][0] = fmaf(a3, b0.x, acc[3][0]); acc[3][1] = fmaf(a3, b0.y, acc[3][1]);
        acc[3][2] = fmaf(a3, b0.z, acc[3][2]); acc[3][3] = fmaf(a3, b0.w, acc[3][3]);
        acc[3][4] = fmaf(a3, b1.x, acc[3][4]); acc[3][5] = fmaf(a3, b1.y, acc[3][5]);
        acc[3][6] = fmaf(a3, b1.z, acc[3][6]); acc[3][7] = fmaf(a3, b1.w, acc[3][7]);
    }
    __syncthreads();  // all U reads done
#pragma unroll
    for (int m = 0; m < 4; m++)
#pragma unroll
        for (int q = 0; q < 8; q++) {
            float v = acc[m][q] + b2s[cg * 8 + q];
            U[rg * 4 + m][cg * 8 + q] = lk(v);
        }
    __syncthreads();

    // phase 3: ed = V @ We3 + be3  (128x16)
    {
        int r = tid >> 1, ch = tid & 1;
        float a3c[8] = {};
        for (int k = 0; k < 64; k++) {
            float a = U[r][k];
            float4 b0 = *(const float4*)&W3[k * 16 + ch * 8];
            float4 b1 = *(const float4*)&W3[k * 16 + ch * 8 + 4];
            a3c[0] = fmaf(a, b0.x, a3c[0]); a3c[1] = fmaf(a, b0.y, a3c[1]);
            a3c[2] = fmaf(a, b0.z, a3c[2]); a3c[3] = fmaf(a, b0.w, a3c[3]);
            a3c[4] = fmaf(a, b1.x, a3c[4]); a3c[5] = fmaf(a, b1.y, a3c[5]);
            a3c[6] = fmaf(a, b1.z, a3c[6]); a3c[7] = fmaf(a, b1.w, a3c[7]);
        }
#pragma unroll
        for (int q = 0; q < 8; q++) ED[r][ch * 8 + q] = a3c[q] + b3s[ch * 8 + q];
    }
    __syncthreads();

    // phase 4: scatter into S (upper block as-is, lower block transposed)
#pragma unroll
    for (int p = 0; p < 2; p++) {
        int t = tid + p * 256;      // 0..511 = 128 edges x 4 rows
        int r = t >> 2, a = t & 3;
        int e = base + r;
        if (e < NE) {
            int i = II[r], j = JJ[r];
            float4 v = make_float4(ED[r][a * 4 + 0], ED[r][a * 4 + 1],
                                   ED[r][a * 4 + 2], ED[r][a * 4 + 3]);
            *(float4*)&S[(4 * i + a) * SDIM + 4 * j] = v;
            float4 w = make_float4(ED[r][0 + a], ED[r][4 + a],
                                   ED[r][8 + a], ED[r][12 + a]);
            *(float4*)&S[(4 * j + a) * SDIM + 4 * i] = w;
        }
    }
}

extern "C" void kernel_launch(void* const* d_in, const int* in_sizes, int n_in,
                              void* d_out, int out_size, void* d_ws, size_t ws_size,
                              hipStream_t stream) {
    const float* x   = (const float*)d_in[0];
    const int*   ud  = (const int*)d_in[3];
    const float* Wg1 = (const float*)d_in[4];
    const float* bg1 = (const float*)d_in[5];
    const float* Wg2 = (const float*)d_in[6];
    const float* bg2 = (const float*)d_in[7];
    const float* Wg3 = (const float*)d_in[8];
    const float* bg3 = (const float*)d_in[9];
    const float* Wn1 = (const float*)d_in[10];
    const float* bn1 = (const float*)d_in[11];
    const float* Wn2 = (const float*)d_in[12];
    const float* bn2 = (const float*)d_in[13];
    const float* Wn3 = (const float*)d_in[14];
    const float* bn3 = (const float*)d_in[15];
    const float* We1 = (const float*)d_in[16];
    const float* be1 = (const float*)d_in[17];
    const float* We2 = (const float*)d_in[18];
    const float* be2 = (const float*)d_in[19];
    const float* We3 = (const float*)d_in[20];
    const float* be3 = (const float*)d_in[21];

    float* out   = (float*)d_out;
    float* h_out = out;                 // 1200*64
    float* S     = out + 76800;         // 4800*4800

    float* ws  = (float*)d_ws;
    float* t1  = ws;                    // 38400
    float* t2  = ws + 38400;            // 38400
    float* t3  = ws + 76800;            // 76800
    float* g   = ws + 153600;           // 76800
    float* cs  = ws + 230400;           // 128 (cs1:32, cs2:32, cs3:64)

    k_init<<<1, 128, 0, stream>>>(cs);
    k_t1<<<38, 256, 0, stream>>>(x, Wg1, t1, cs);
    k_t2<<<38, 256, 0, stream>>>(t1, cs, bg1, Wg2, t2, cs + 32);
    k_t3<<<38, 256, 0, stream>>>(t2, cs + 32, bg2, Wg3, t3, cs + 64);
    k_node<<<19, 256, 0, stream>>>(t3, cs + 64, bg3, We1, Wn1, bn1, Wn2, bn2,
                                   Wn3, bn3, h_out, g, S);
    k_edge<<<5621, 256, 0, stream>>>(ud, g, be1, We2, be2, We3, be3, S);
}

// Round 2
// 140.663 us; speedup vs baseline: 1.3228x; 1.3228x over previous
//
#include <hip/hip_runtime.h>

#define NN 1200
#define NE 719400
#define SDIM 4800

typedef __attribute__((ext_vector_type(8))) short bf16x8;
typedef __attribute__((ext_vector_type(4))) float f32x4;

static __device__ __constant__ int SMAT[16] = {0,1,2,3,1,4,5,6,2,5,7,8,3,6,8,9};

__device__ __forceinline__ float lk(float v) { return v >= 0.f ? v : 0.1f * v; }

// split one f32 into bf16 hi (RNE) + bf16 lo (RNE of residual)
__device__ __forceinline__ void split8(const float* u, bf16x8& hi, bf16x8& lo) {
#pragma unroll
    for (int e = 0; e < 8; e++) {
        unsigned x = __float_as_uint(u[e]);
        unsigned r = x + 0x7FFFu + ((x >> 16) & 1u);
        hi[e] = (short)(r >> 16);
        float hf = __uint_as_float(r & 0xFFFF0000u);
        float s = u[e] - hf;
        unsigned v = __float_as_uint(s);
        unsigned w = v + 0x7FFFu + ((v >> 16) & 1u);
        lo[e] = (short)(w >> 16);
    }
}

__device__ __forceinline__ uint2 split2(float a0, float a1) {
    unsigned u0 = __float_as_uint(a0), u1 = __float_as_uint(a1);
    unsigned r0 = u0 + 0x7FFFu + ((u0 >> 16) & 1u);
    unsigned r1 = u1 + 0x7FFFu + ((u1 >> 16) & 1u);
    float h0 = __uint_as_float(r0 & 0xFFFF0000u);
    float h1 = __uint_as_float(r1 & 0xFFFF0000u);
    float s0 = a0 - h0, s1 = a1 - h1;
    unsigned v0 = __float_as_uint(s0), v1 = __float_as_uint(s1);
    unsigned t0 = v0 + 0x7FFFu + ((v0 >> 16) & 1u);
    unsigned t1 = v1 + 0x7FFFu + ((v1 >> 16) & 1u);
    unsigned hi = (r0 >> 16) | (r1 & 0xFFFF0000u);
    unsigned lo = (t0 >> 16) | (t1 & 0xFFFF0000u);
    return make_uint2(hi, lo);
}

// ---------------- init ----------------
__global__ void k_init(float* cs) {
    int t = threadIdx.x;
    if (t < 128) cs[t] = 0.f;
}

// ---------------- prep: split We2/We3 into per-lane MFMA B-fragments ----------------
// W2F layout: [(ks*4+nf)*64 + lane]*8 u32 : 4 u32 hi pairs then 4 u32 lo pairs
// B-frag element e: k = ks*32 + (lane>>4)*8 + e, n = (lane&15) + 16*nf
__global__ void k_prep(const float* __restrict__ We2, const float* __restrict__ We3,
                       unsigned* __restrict__ W2F, unsigned* __restrict__ W3F) {
    int t = blockIdx.x * 256 + threadIdx.x;
    if (t < 512) {
        int lane = t & 63, nf = (t >> 6) & 3, ks = t >> 8;
        int n = (lane & 15) + 16 * nf;
        int kb = ks * 32 + (lane >> 4) * 8;
        unsigned* dst = W2F + t * 8;
#pragma unroll
        for (int p = 0; p < 4; p++) {
            float a0 = We2[(kb + 2 * p) * 64 + n];
            float a1 = We2[(kb + 2 * p + 1) * 64 + n];
            uint2 hl = split2(a0, a1);
            dst[p] = hl.x; dst[4 + p] = hl.y;
        }
    } else if (t < 640) {
        int q = t - 512;
        int lane = q & 63, ks = q >> 6;
        int n = lane & 15;
        int kb = ks * 32 + (lane >> 4) * 8;
        unsigned* dst = W3F + q * 8;
#pragma unroll
        for (int p = 0; p < 4; p++) {
            float a0 = We3[(kb + 2 * p) * 16 + n];
            float a1 = We3[(kb + 2 * p + 1) * 16 + n];
            uint2 hl = split2(a0, a1);
            dst[p] = hl.x; dst[4 + p] = hl.y;
        }
    }
}

// ---------------- GCN stage 1 ----------------
__global__ __launch_bounds__(256) void k_t1(const float* __restrict__ x,
                                            const float* __restrict__ Wg1,
                                            float* __restrict__ t1,
                                            float* __restrict__ cs1) {
    int T = blockIdx.x * 256 + threadIdx.x;
    int c = T & 31, rs = T >> 5;
    float w[6];
#pragma unroll
    for (int k = 0; k < 6; k++) w[k] = Wg1[k * 32 + c];
    float loc = 0.f;
    for (int r = rs; r < NN; r += 304) {
        float acc = 0.f;
#pragma unroll
        for (int k = 0; k < 6; k++) acc = fmaf(x[r * 16 + k], w[k], acc);
        t1[r * 32 + c] = acc;
        loc += acc;
    }
    atomicAdd(&cs1[c], loc);
}

// ---------------- GCN stage 2 ----------------
__global__ __launch_bounds__(256) void k_t2(const float* __restrict__ t1,
                                            const float* __restrict__ cs1,
                                            const float* __restrict__ bg1,
                                            const float* __restrict__ Wg2,
                                            float* __restrict__ t2,
                                            float* __restrict__ cs2) {
    int T = blockIdx.x * 256 + threadIdx.x;
    int c = T & 31, rs = T >> 5;
    const float inv = 1.0f / 1199.0f;
    float p[32], w[32];
#pragma unroll
    for (int k = 0; k < 32; k++) {
        p[k] = fmaf(cs1[k], inv, bg1[k]);
        w[k] = Wg2[k * 32 + c];
    }
    float loc = 0.f;
    for (int r = rs; r < NN; r += 304) {
        float acc = 0.f;
#pragma unroll
        for (int k = 0; k < 32; k++) {
            float h = lk(fmaf(-t1[r * 32 + k], inv, p[k]));
            acc = fmaf(h, w[k], acc);
        }
        t2[r * 32 + c] = acc;
        loc += acc;
    }
    atomicAdd(&cs2[c], loc);
}

// ---------------- GCN stage 3 ----------------
__global__ __launch_bounds__(256) void k_t3(const float* __restrict__ t2,
                                            const float* __restrict__ cs2,
                                            const float* __restrict__ bg2,
                                            const float* __restrict__ Wg3,
                                            float* __restrict__ t3,
                                            float* __restrict__ cs3) {
    int T = blockIdx.x * 256 + threadIdx.x;
    int c = T & 63, rs = T >> 6;
    const float inv = 1.0f / 1199.0f;
    float p[32], w[32];
#pragma unroll
    for (int k = 0; k < 32; k++) {
        p[k] = fmaf(cs2[k], inv, bg2[k]);
        w[k] = Wg3[k * 64 + c];
    }
    float loc = 0.f;
    for (int r = rs; r < NN; r += 152) {
        float acc = 0.f;
#pragma unroll
        for (int k = 0; k < 32; k++) {
            float h = lk(fmaf(-t2[r * 32 + k], inv, p[k]));
            acc = fmaf(h, w[k], acc);
        }
        t3[r * 64 + c] = acc;
        loc += acc;
    }
    atomicAdd(&cs3[c], loc);
}

// ---------------- shared 2x8 register-tile GEMM from LDS ----------------
__device__ __forceinline__ void gemm2x8(const float A[64][65], const float* W,
                                        int rg, int cg, float acc[2][8]) {
#pragma unroll 8
    for (int k = 0; k < 64; k++) {
        float a0 = A[rg * 2 + 0][k];
        float a1 = A[rg * 2 + 1][k];
        float4 b0 = *(const float4*)&W[k * 64 + cg * 8];
        float4 b1 = *(const float4*)&W[k * 64 + cg * 8 + 4];
        acc[0][0] = fmaf(a0, b0.x, acc[0][0]); acc[0][1] = fmaf(a0, b0.y, acc[0][1]);
        acc[0][2] = fmaf(a0, b0.z, acc[0][2]); acc[0][3] = fmaf(a0, b0.w, acc[0][3]);
        acc[0][4] = fmaf(a0, b1.x, acc[0][4]); acc[0][5] = fmaf(a0, b1.y, acc[0][5]);
        acc[0][6] = fmaf(a0, b1.z, acc[0][6]); acc[0][7] = fmaf(a0, b1.w, acc[0][7]);
        acc[1][0] = fmaf(a1, b0.x, acc[1][0]); acc[1][1] = fmaf(a1, b0.y, acc[1][1]);
        acc[1][2] = fmaf(a1, b0.z, acc[1][2]); acc[1][3] = fmaf(a1, b0.w, acc[1][3]);
        acc[1][4] = fmaf(a1, b1.x, acc[1][4]); acc[1][5] = fmaf(a1, b1.y, acc[1][5]);
        acc[1][6] = fmaf(a1, b1.z, acc[1][6]); acc[1][7] = fmaf(a1, b1.w, acc[1][7]);
    }
}

// ---------------- node kernel (unchanged) ----------------
__global__ __launch_bounds__(256) void k_node(
    const float* __restrict__ t3, const float* __restrict__ cs3,
    const float* __restrict__ bg3,
    const float* __restrict__ We1,
    const float* __restrict__ Wn1, const float* __restrict__ bn1,
    const float* __restrict__ Wn2, const float* __restrict__ bn2,
    const float* __restrict__ Wn3, const float* __restrict__ bn3,
    float* __restrict__ h_out, float* __restrict__ g_out,
    float* __restrict__ S) {
    __shared__ float H[64][65];
    __shared__ float N1s[64][65];
    __shared__ float WA[4096];
    __shared__ float WB[4096];
    __shared__ float WC[4096];
    __shared__ float WD[640];
    __shared__ float VD[64][12];
    __shared__ float sbn1[64], sbn2[64], sbn3[16];

    const int tid = threadIdx.x;
    const int r0 = blockIdx.x * 64;
    const float inv = 1.0f / 1199.0f;

    for (int t = tid; t < 1024; t += 256) {
        ((float4*)WA)[t] = ((const float4*)We1)[t];
        ((float4*)WB)[t] = ((const float4*)Wn1)[t];
        ((float4*)WC)[t] = ((const float4*)Wn2)[t];
    }
    for (int t = tid; t < 640; t += 256) WD[t] = Wn3[t];
    if (tid < 64) { sbn1[tid] = bn1[tid]; sbn2[tid] = bn2[tid]; }
    if (tid < 10) sbn3[tid] = bn3[tid];

    for (int t = tid; t < 4096; t += 256) {
        int i = t >> 6, c = t & 63;
        int row = r0 + i;
        float v = 0.f;
        if (row < NN) {
            v = fmaf(cs3[c] - t3[row * 64 + c], inv, bg3[c]);
            h_out[row * 64 + c] = v;
        }
        H[i][c] = v;
    }
    __syncthreads();

    const int rg = tid >> 3;
    const int cg = tid & 7;

    {
        float acc[2][8] = {};
        gemm2x8(H, WA, rg, cg, acc);
#pragma unroll
        for (int m = 0; m < 2; m++) {
            int row = r0 + rg * 2 + m;
            if (row < NN) {
                *(float4*)&g_out[row * 64 + cg * 8]     = make_float4(acc[m][0], acc[m][1], acc[m][2], acc[m][3]);
                *(float4*)&g_out[row * 64 + cg * 8 + 4] = make_float4(acc[m][4], acc[m][5], acc[m][6], acc[m][7]);
            }
        }
    }
    {
        float acc[2][8] = {};
        gemm2x8(H, WB, rg, cg, acc);
#pragma unroll
        for (int m = 0; m < 2; m++)
#pragma unroll
            for (int q = 0; q < 8; q++)
                N1s[rg * 2 + m][cg * 8 + q] = lk(acc[m][q] + sbn1[cg * 8 + q]);
    }
    __syncthreads();
    {
        float acc[2][8] = {};
        gemm2x8(N1s, WC, rg, cg, acc);
#pragma unroll
        for (int m = 0; m < 2; m++)
#pragma unroll
            for (int q = 0; q < 8; q++)
                H[rg * 2 + m][cg * 8 + q] = lk(acc[m][q] + sbn2[cg * 8 + q]);
    }
    __syncthreads();
    for (int t = tid; t < 640; t += 256) {
        int r = t / 10, c = t % 10;
        float acc = sbn3[c];
        for (int k = 0; k < 64; k++) acc = fmaf(H[r][k], WD[k * 10 + c], acc);
        VD[r][c] = acc;
    }
    __syncthreads();
    {
        int r = tid >> 2, a = tid & 3;
        int row = r0 + r;
        if (row < NN) {
            float4 v = make_float4(VD[r][SMAT[a * 4 + 0]], VD[r][SMAT[a * 4 + 1]],
                                   VD[r][SMAT[a * 4 + 2]], VD[r][SMAT[a * 4 + 3]]);
            *(float4*)&S[(4 * row + a) * SDIM + 4 * row] = v;
        }
    }
}

// ---------------- edge kernel: 128 edges/WG, split-bf16 MFMA ----------------
__global__ __launch_bounds__(256) void k_edge(const int* __restrict__ ud,
                                              const float* __restrict__ g,
                                              const float* __restrict__ be1,
                                              const float* __restrict__ be2,
                                              const float* __restrict__ be3,
                                              const unsigned* __restrict__ W2F,
                                              const unsigned* __restrict__ W3F,
                                              float* __restrict__ S) {
    __shared__ float VB[128][68];
    __shared__ float ED[128][16];
    __shared__ int II[128], JJ[128];

    const int tid = threadIdx.x;
    const int wave = tid >> 6, lane = tid & 63;
    const int lrow = lane & 15, lgrp = lane >> 4;
    const int base = blockIdx.x * 128;

    if (tid < 128) {
        int e = base + tid;
        int2 ij = make_int2(0, 0);
        if (e < NE) ij = ((const int2*)ud)[e];
        II[tid] = ij.x; JJ[tid] = ij.y;
    }
    __syncthreads();

    // A-fragments of U = lk(g[i]+g[j]+be1), computed per-lane, split hi/lo.
    // A layout: lane holds row (lane&15), k = (lane>>4)*8 + e  (per 16x16x32 frag)
    bf16x8 Ahi[2][2], Alo[2][2];
#pragma unroll
    for (int mf = 0; mf < 2; mf++) {
        int r = wave * 32 + mf * 16 + lrow;
        const float* gi = g + II[r] * 64;
        const float* gj = g + JJ[r] * 64;
#pragma unroll
        for (int ks = 0; ks < 2; ks++) {
            int kb = ks * 32 + lgrp * 8;
            f32x4 a0 = *(const f32x4*)(gi + kb);
            f32x4 a1 = *(const f32x4*)(gi + kb + 4);
            f32x4 b0 = *(const f32x4*)(gj + kb);
            f32x4 b1 = *(const f32x4*)(gj + kb + 4);
            f32x4 c0 = *(const f32x4*)(be1 + kb);
            f32x4 c1 = *(const f32x4*)(be1 + kb + 4);
            float u[8];
#pragma unroll
            for (int e = 0; e < 4; e++) {
                u[e]     = lk(a0[e] + b0[e] + c0[e]);
                u[4 + e] = lk(a1[e] + b1[e] + c1[e]);
            }
            split8(u, Ahi[mf][ks], Alo[mf][ks]);
        }
    }

    // layer 2: V' = U @ We2, 3-term split MFMA
    f32x4 acc[2][4];
#pragma unroll
    for (int mf = 0; mf < 2; mf++)
#pragma unroll
        for (int nf = 0; nf < 4; nf++)
#pragma unroll
            for (int q = 0; q < 4; q++) acc[mf][nf][q] = 0.f;

#pragma unroll
    for (int nf = 0; nf < 4; nf++)
#pragma unroll
        for (int ks = 0; ks < 2; ks++) {
            const unsigned* p = W2F + ((ks * 4 + nf) * 64 + lane) * 8;
            bf16x8 bh = *(const bf16x8*)p;
            bf16x8 bl = *(const bf16x8*)(p + 4);
#pragma unroll
            for (int mf = 0; mf < 2; mf++) {
                acc[mf][nf] = __builtin_amdgcn_mfma_f32_16x16x32_bf16(Ahi[mf][ks], bh, acc[mf][nf], 0, 0, 0);
                acc[mf][nf] = __builtin_amdgcn_mfma_f32_16x16x32_bf16(Alo[mf][ks], bh, acc[mf][nf], 0, 0, 0);
                acc[mf][nf] = __builtin_amdgcn_mfma_f32_16x16x32_bf16(Ahi[mf][ks], bl, acc[mf][nf], 0, 0, 0);
            }
        }

    // activation + bias, store V row-major to LDS (C layout: col=lane&15, row=4*(lane>>4)+reg)
#pragma unroll
    for (int nf = 0; nf < 4; nf++) {
        float b2 = be2[lrow + 16 * nf];
#pragma unroll
        for (int mf = 0; mf < 2; mf++)
#pragma unroll
            for (int rg = 0; rg < 4; rg++)
                VB[wave * 32 + mf * 16 + lgrp * 4 + rg][lrow + 16 * nf] = lk(acc[mf][nf][rg] + b2);
    }
    __syncthreads();

    // layer 3: ed = V @ We3, V re-read as A-fragments from LDS
    f32x4 acc3[2];
#pragma unroll
    for (int mf = 0; mf < 2; mf++)
#pragma unroll
        for (int q = 0; q < 4; q++) acc3[mf][q] = 0.f;

#pragma unroll
    for (int ks = 0; ks < 2; ks++) {
        const unsigned* p = W3F + (ks * 64 + lane) * 8;
        bf16x8 bh = *(const bf16x8*)p;
        bf16x8 bl = *(const bf16x8*)(p + 4);
#pragma unroll
        for (int mf = 0; mf < 2; mf++) {
            int row = wave * 32 + mf * 16 + lrow;
            int kb = ks * 32 + lgrp * 8;
            f32x4 v0 = *(const f32x4*)&VB[row][kb];
            f32x4 v1 = *(const f32x4*)&VB[row][kb + 4];
            float u[8] = {v0[0], v0[1], v0[2], v0[3], v1[0], v1[1], v1[2], v1[3]};
            bf16x8 vh, vl;
            split8(u, vh, vl);
            acc3[mf] = __builtin_amdgcn_mfma_f32_16x16x32_bf16(vh, bh, acc3[mf], 0, 0, 0);
            acc3[mf] = __builtin_amdgcn_mfma_f32_16x16x32_bf16(vl, bh, acc3[mf], 0, 0, 0);
            acc3[mf] = __builtin_amdgcn_mfma_f32_16x16x32_bf16(vh, bl, acc3[mf], 0, 0, 0);
        }
    }
    {
        float b3 = be3[lrow];
#pragma unroll
        for (int mf = 0; mf < 2; mf++)
#pragma unroll
            for (int rg = 0; rg < 4; rg++)
                ED[wave * 32 + mf * 16 + lgrp * 4 + rg][lrow] = acc3[mf][rg] + b3;
    }
    __syncthreads();

    // scatter into S (upper block as-is, lower block transposed)
#pragma unroll
    for (int p = 0; p < 2; p++) {
        int t = tid + p * 256;
        int r = t >> 2, a = t & 3;
        int e = base + r;
        if (e < NE) {
            int i = II[r], j = JJ[r];
            float4 v = make_float4(ED[r][a * 4 + 0], ED[r][a * 4 + 1],
                                   ED[r][a * 4 + 2], ED[r][a * 4 + 3]);
            *(float4*)&S[(4 * i + a) * SDIM + 4 * j] = v;
            float4 w = make_float4(ED[r][0 + a], ED[r][4 + a],
                                   ED[r][8 + a], ED[r][12 + a]);
            *(float4*)&S[(4 * j + a) * SDIM + 4 * i] = w;
        }
    }
}

extern "C" void kernel_launch(void* const* d_in, const int* in_sizes, int n_in,
                              void* d_out, int out_size, void* d_ws, size_t ws_size,
                              hipStream_t stream) {
    const float* x   = (const float*)d_in[0];
    const int*   ud  = (const int*)d_in[3];
    const float* Wg1 = (const float*)d_in[4];
    const float* bg1 = (const float*)d_in[5];
    const float* Wg2 = (const float*)d_in[6];
    const float* bg2 = (const float*)d_in[7];
    const float* Wg3 = (const float*)d_in[8];
    const float* bg3 = (const float*)d_in[9];
    const float* Wn1 = (const float*)d_in[10];
    const float* bn1 = (const float*)d_in[11];
    const float* Wn2 = (const float*)d_in[12];
    const float* bn2 = (const float*)d_in[13];
    const float* Wn3 = (const float*)d_in[14];
    const float* bn3 = (const float*)d_in[15];
    const float* We1 = (const float*)d_in[16];
    const float* be1 = (const float*)d_in[17];
    const float* We2 = (const float*)d_in[18];
    const float* be2 = (const float*)d_in[19];
    const float* We3 = (const float*)d_in[20];
    const float* be3 = (const float*)d_in[21];

    float* out   = (float*)d_out;
    float* h_out = out;                 // 1200*64
    float* S     = out + 76800;         // 4800*4800

    float* ws  = (float*)d_ws;
    float* t1  = ws;                    // 38400
    float* t2  = ws + 38400;            // 38400
    float* t3  = ws + 76800;            // 76800
    float* g   = ws + 153600;           // 76800
    float* cs  = ws + 230400;           // 128
    unsigned* W2F = (unsigned*)(ws + 230528);  // 4096 u32
    unsigned* W3F = W2F + 4096;                // 1024 u32

    k_init<<<1, 128, 0, stream>>>(cs);
    k_prep<<<3, 256, 0, stream>>>(We2, We3, W2F, W3F);
    k_t1<<<38, 256, 0, stream>>>(x, Wg1, t1, cs);
    k_t2<<<38, 256, 0, stream>>>(t1, cs, bg1, Wg2, t2, cs + 32);
    k_t3<<<38, 256, 0, stream>>>(t2, cs + 32, bg2, Wg3, t3, cs + 64);
    k_node<<<19, 256, 0, stream>>>(t3, cs + 64, bg3, We1, Wn1, bn1, Wn2, bn2,
                                   Wn3, bn3, h_out, g, S);
    k_edge<<<5621, 256, 0, stream>>>(ud, g, be1, be2, be3, W2F, W3F, S);
}

// Round 3
// 125.336 us; speedup vs baseline: 1.4846x; 1.1223x over previous
//
#include <hip/hip_runtime.h>

#define NN 1200
#define NE 719400
#define SDIM 4800

typedef __attribute__((ext_vector_type(8))) short bf16x8;
typedef __attribute__((ext_vector_type(4))) short bf16x4;
typedef __attribute__((ext_vector_type(4))) float f32x4;

static __device__ __constant__ int SMAT[16] = {0,1,2,3,1,4,5,6,2,5,7,8,3,6,8,9};

__device__ __forceinline__ float lk(float v) { return v >= 0.f ? v : 0.1f * v; }

#if __has_builtin(__builtin_amdgcn_mfma_f32_16x16x16bf16_1k)
__device__ __forceinline__ f32x4 mfma1616(bf16x4 a, bf16x4 b, f32x4 c) {
    return __builtin_amdgcn_mfma_f32_16x16x16bf16_1k(a, b, c, 0, 0, 0);
}
#else
__device__ __forceinline__ f32x4 mfma1616(bf16x4 a, bf16x4 b, f32x4 c) {
    asm volatile("v_mfma_f32_16x16x16_bf16 %0, %1, %2, %0\n\ts_nop 7\n\ts_nop 7"
                 : "+v"(c) : "v"(a), "v"(b));
    return c;
}
#endif

// split f32 -> bf16 hi (RNE) + bf16 lo (RNE of residual)
__device__ __forceinline__ void split8(const float* u, bf16x8& hi, bf16x8& lo) {
#pragma unroll
    for (int e = 0; e < 8; e++) {
        unsigned x = __float_as_uint(u[e]);
        unsigned r = x + 0x7FFFu + ((x >> 16) & 1u);
        hi[e] = (short)(r >> 16);
        float hf = __uint_as_float(r & 0xFFFF0000u);
        float s = u[e] - hf;
        unsigned v = __float_as_uint(s);
        unsigned w = v + 0x7FFFu + ((v >> 16) & 1u);
        lo[e] = (short)(w >> 16);
    }
}

__device__ __forceinline__ void split4(const float* u, bf16x4& hi, bf16x4& lo) {
#pragma unroll
    for (int e = 0; e < 4; e++) {
        unsigned x = __float_as_uint(u[e]);
        unsigned r = x + 0x7FFFu + ((x >> 16) & 1u);
        hi[e] = (short)(r >> 16);
        float hf = __uint_as_float(r & 0xFFFF0000u);
        float s = u[e] - hf;
        unsigned v = __float_as_uint(s);
        unsigned w = v + 0x7FFFu + ((v >> 16) & 1u);
        lo[e] = (short)(w >> 16);
    }
}

__device__ __forceinline__ uint2 split2(float a0, float a1) {
    unsigned u0 = __float_as_uint(a0), u1 = __float_as_uint(a1);
    unsigned r0 = u0 + 0x7FFFu + ((u0 >> 16) & 1u);
    unsigned r1 = u1 + 0x7FFFu + ((u1 >> 16) & 1u);
    float h0 = __uint_as_float(r0 & 0xFFFF0000u);
    float h1 = __uint_as_float(r1 & 0xFFFF0000u);
    float s0 = a0 - h0, s1 = a1 - h1;
    unsigned v0 = __float_as_uint(s0), v1 = __float_as_uint(s1);
    unsigned t0 = v0 + 0x7FFFu + ((v0 >> 16) & 1u);
    unsigned t1 = v1 + 0x7FFFu + ((v1 >> 16) & 1u);
    unsigned hi = (r0 >> 16) | (r1 & 0xFFFF0000u);
    unsigned lo = (t0 >> 16) | (t1 & 0xFFFF0000u);
    return make_uint2(hi, lo);
}

// ---------------- prep: We2^T A-frags (16x16x32), We3^T A-frags (16x16x16), cs zero ----
// W2F: block b = (mt*2+ks)*2 + h (h=0 hi,1 lo): W2F[b*256 + lane*4 + p]
//   elem e of lane: A[m][k] = We2[ks*32+(lane>>4)*8+e][mt*16+(lane&15)]
// W3F: block b = kb*2 + h: W3F[b*128 + lane*2 + p]
//   elem e: A3[m][k] = We3[kb*16+(lane>>4)*4+e][lane&15]
__global__ void k_prep(const float* __restrict__ We2, const float* __restrict__ We3,
                       unsigned* __restrict__ W2F, unsigned* __restrict__ W3F,
                       float* __restrict__ cs) {
    int t = blockIdx.x * 256 + threadIdx.x;
    if (t < 512) {
        int lane = t & 63, ks = (t >> 6) & 1, mt = t >> 7;
        int m = mt * 16 + (lane & 15);
        int kb = ks * 32 + (lane >> 4) * 8;
        unsigned hi[4], lo[4];
#pragma unroll
        for (int p = 0; p < 4; p++) {
            float a0 = We2[(kb + 2 * p) * 64 + m];
            float a1 = We2[(kb + 2 * p + 1) * 64 + m];
            uint2 hl = split2(a0, a1);
            hi[p] = hl.x; lo[p] = hl.y;
        }
        *(uint4*)(W2F + ((mt * 2 + ks) * 2 + 0) * 256 + lane * 4) = make_uint4(hi[0], hi[1], hi[2], hi[3]);
        *(uint4*)(W2F + ((mt * 2 + ks) * 2 + 1) * 256 + lane * 4) = make_uint4(lo[0], lo[1], lo[2], lo[3]);
    } else if (t < 768) {
        int q = t - 512;
        int lane = q & 63, kb = q >> 6;
        int c = lane & 15;
        int k0 = kb * 16 + (lane >> 4) * 4;
        unsigned hi[2], lo[2];
#pragma unroll
        for (int p = 0; p < 2; p++) {
            float a0 = We3[(k0 + 2 * p) * 16 + c];
            float a1 = We3[(k0 + 2 * p + 1) * 16 + c];
            uint2 hl = split2(a0, a1);
            hi[p] = hl.x; lo[p] = hl.y;
        }
        *(uint2*)(W3F + (kb * 2 + 0) * 128 + lane * 2) = make_uint2(hi[0], hi[1]);
        *(uint2*)(W3F + (kb * 2 + 1) * 128 + lane * 2) = make_uint2(lo[0], lo[1]);
    } else if (t < 896) {
        cs[t - 768] = 0.f;
    }
}

// ---------------- GCN stage 1 ----------------
__global__ __launch_bounds__(256) void k_t1(const float* __restrict__ x,
                                            const float* __restrict__ Wg1,
                                            float* __restrict__ t1,
                                            float* __restrict__ cs1) {
    int T = blockIdx.x * 256 + threadIdx.x;
    int c = T & 31, rs = T >> 5;
    float w[6];
#pragma unroll
    for (int k = 0; k < 6; k++) w[k] = Wg1[k * 32 + c];
    float loc = 0.f;
    for (int r = rs; r < NN; r += 304) {
        float acc = 0.f;
#pragma unroll
        for (int k = 0; k < 6; k++) acc = fmaf(x[r * 16 + k], w[k], acc);
        t1[r * 32 + c] = acc;
        loc += acc;
    }
    atomicAdd(&cs1[c], loc);
}

// ---------------- GCN stage 2 ----------------
__global__ __launch_bounds__(256) void k_t2(const float* __restrict__ t1,
                                            const float* __restrict__ cs1,
                                            const float* __restrict__ bg1,
                                            const float* __restrict__ Wg2,
                                            float* __restrict__ t2,
                                            float* __restrict__ cs2) {
    int T = blockIdx.x * 256 + threadIdx.x;
    int c = T & 31, rs = T >> 5;
    const float inv = 1.0f / 1199.0f;
    float p[32], w[32];
#pragma unroll
    for (int k = 0; k < 32; k++) {
        p[k] = fmaf(cs1[k], inv, bg1[k]);
        w[k] = Wg2[k * 32 + c];
    }
    float loc = 0.f;
    for (int r = rs; r < NN; r += 304) {
        float acc = 0.f;
#pragma unroll
        for (int k = 0; k < 32; k++) {
            float h = lk(fmaf(-t1[r * 32 + k], inv, p[k]));
            acc = fmaf(h, w[k], acc);
        }
        t2[r * 32 + c] = acc;
        loc += acc;
    }
    atomicAdd(&cs2[c], loc);
}

// ---------------- GCN stage 3 ----------------
__global__ __launch_bounds__(256) void k_t3(const float* __restrict__ t2,
                                            const float* __restrict__ cs2,
                                            const float* __restrict__ bg2,
                                            const float* __restrict__ Wg3,
                                            float* __restrict__ t3,
                                            float* __restrict__ cs3) {
    int T = blockIdx.x * 256 + threadIdx.x;
    int c = T & 63, rs = T >> 6;
    const float inv = 1.0f / 1199.0f;
    float p[32], w[32];
#pragma unroll
    for (int k = 0; k < 32; k++) {
        p[k] = fmaf(cs2[k], inv, bg2[k]);
        w[k] = Wg3[k * 64 + c];
    }
    float loc = 0.f;
    for (int r = rs; r < NN; r += 152) {
        float acc = 0.f;
#pragma unroll
        for (int k = 0; k < 32; k++) {
            float h = lk(fmaf(-t2[r * 32 + k], inv, p[k]));
            acc = fmaf(h, w[k], acc);
        }
        t3[r * 64 + c] = acc;
        loc += acc;
    }
    atomicAdd(&cs3[c], loc);
}

// ---------------- k_g: h = GCN3 output, g = h @ We1 ----------------
__global__ __launch_bounds__(256) void k_g(const float* __restrict__ t3,
                                           const float* __restrict__ cs3,
                                           const float* __restrict__ bg3,
                                           const float* __restrict__ We1,
                                           float* __restrict__ h_out,
                                           float* __restrict__ g_out) {
    __shared__ float H[32][65];
    __shared__ float W[4096];
    const int tid = threadIdx.x;
    const int r0 = blockIdx.x * 32;
    const float inv = 1.0f / 1199.0f;

    for (int t = tid; t < 1024; t += 256) ((float4*)W)[t] = ((const float4*)We1)[t];
    for (int t = tid; t < 2048; t += 256) {
        int i = t >> 6, c = t & 63;
        int row = r0 + i;
        float v = 0.f;
        if (row < NN) {
            v = fmaf(cs3[c] - t3[row * 64 + c], inv, bg3[c]);
            h_out[row * 64 + c] = v;
        }
        H[i][c] = v;
    }
    __syncthreads();

    int rg = tid >> 3, cg = tid & 7;  // row rg (0..31), cols cg*8..+7
    float acc[8] = {};
#pragma unroll 8
    for (int k = 0; k < 64; k++) {
        float a = H[rg][k];
        float4 b0 = *(const float4*)&W[k * 64 + cg * 8];
        float4 b1 = *(const float4*)&W[k * 64 + cg * 8 + 4];
        acc[0] = fmaf(a, b0.x, acc[0]); acc[1] = fmaf(a, b0.y, acc[1]);
        acc[2] = fmaf(a, b0.z, acc[2]); acc[3] = fmaf(a, b0.w, acc[3]);
        acc[4] = fmaf(a, b1.x, acc[4]); acc[5] = fmaf(a, b1.y, acc[5]);
        acc[6] = fmaf(a, b1.z, acc[6]); acc[7] = fmaf(a, b1.w, acc[7]);
    }
    int row = r0 + rg;
    if (row < NN) {
        *(float4*)&g_out[row * 64 + cg * 8]     = make_float4(acc[0], acc[1], acc[2], acc[3]);
        *(float4*)&g_out[row * 64 + cg * 8 + 4] = make_float4(acc[4], acc[5], acc[6], acc[7]);
    }
}

// ---------------- k_vd: node MLP + diagonal Vsym blocks ----------------
__global__ __launch_bounds__(256) void k_vd(const float* __restrict__ h,
                                            const float* __restrict__ Wn1, const float* __restrict__ bn1,
                                            const float* __restrict__ Wn2, const float* __restrict__ bn2,
                                            const float* __restrict__ Wn3, const float* __restrict__ bn3,
                                            float* __restrict__ S) {
    __shared__ float H[32][65];
    __shared__ float N1[32][65];
    __shared__ float WB[4096];
    __shared__ float WC[4096];
    __shared__ float WD[640];
    __shared__ float VD[32][12];
    __shared__ float sb1[64], sb2[64], sb3[16];

    const int tid = threadIdx.x;
    const int r0 = blockIdx.x * 32;

    for (int t = tid; t < 1024; t += 256) {
        ((float4*)WB)[t] = ((const float4*)Wn1)[t];
        ((float4*)WC)[t] = ((const float4*)Wn2)[t];
    }
    for (int t = tid; t < 640; t += 256) WD[t] = Wn3[t];
    if (tid < 64) { sb1[tid] = bn1[tid]; sb2[tid] = bn2[tid]; }
    if (tid < 10) sb3[tid] = bn3[tid];

    for (int t = tid; t < 2048; t += 256) {
        int i = t >> 6, c = t & 63;
        int row = r0 + i;
        H[i][c] = (row < NN) ? h[row * 64 + c] : 0.f;
    }
    __syncthreads();

    int rg = tid >> 3, cg = tid & 7;
    {
        float acc[8] = {};
#pragma unroll 8
        for (int k = 0; k < 64; k++) {
            float a = H[rg][k];
            float4 b0 = *(const float4*)&WB[k * 64 + cg * 8];
            float4 b1 = *(const float4*)&WB[k * 64 + cg * 8 + 4];
            acc[0] = fmaf(a, b0.x, acc[0]); acc[1] = fmaf(a, b0.y, acc[1]);
            acc[2] = fmaf(a, b0.z, acc[2]); acc[3] = fmaf(a, b0.w, acc[3]);
            acc[4] = fmaf(a, b1.x, acc[4]); acc[5] = fmaf(a, b1.y, acc[5]);
            acc[6] = fmaf(a, b1.z, acc[6]); acc[7] = fmaf(a, b1.w, acc[7]);
        }
#pragma unroll
        for (int q = 0; q < 8; q++) N1[rg][cg * 8 + q] = lk(acc[q] + sb1[cg * 8 + q]);
    }
    __syncthreads();
    {
        float acc[8] = {};
#pragma unroll 8
        for (int k = 0; k < 64; k++) {
            float a = N1[rg][k];
            float4 b0 = *(const float4*)&WC[k * 64 + cg * 8];
            float4 b1 = *(const float4*)&WC[k * 64 + cg * 8 + 4];
            acc[0] = fmaf(a, b0.x, acc[0]); acc[1] = fmaf(a, b0.y, acc[1]);
            acc[2] = fmaf(a, b0.z, acc[2]); acc[3] = fmaf(a, b0.w, acc[3]);
            acc[4] = fmaf(a, b1.x, acc[4]); acc[5] = fmaf(a, b1.y, acc[5]);
            acc[6] = fmaf(a, b1.z, acc[6]); acc[7] = fmaf(a, b1.w, acc[7]);
        }
#pragma unroll
        for (int q = 0; q < 8; q++) H[rg][cg * 8 + q] = lk(acc[q] + sb2[cg * 8 + q]);
    }
    __syncthreads();
    for (int t = tid; t < 320; t += 256) {
        int r = t / 10, c = t % 10;
        float acc = sb3[c];
        for (int k = 0; k < 64; k++) acc = fmaf(H[r][k], WD[k * 10 + c], acc);
        VD[r][c] = acc;
    }
    __syncthreads();
    if (tid < 128) {
        int r = tid >> 2, a = tid & 3;
        int row = r0 + r;
        if (row < NN) {
            float4 v = make_float4(VD[r][SMAT[a * 4 + 0]], VD[r][SMAT[a * 4 + 1]],
                                   VD[r][SMAT[a * 4 + 2]], VD[r][SMAT[a * 4 + 3]]);
            *(float4*)&S[(4 * row + a) * SDIM + 4 * row] = v;
        }
    }
}

// ---------------- edge kernel: 128 edges/WG, 32/wave, no barriers ----------------
__global__ __launch_bounds__(256) void k_edge(const int* __restrict__ ud,
                                              const float* __restrict__ g,
                                              const float* __restrict__ be1,
                                              const float* __restrict__ be2,
                                              const float* __restrict__ be3,
                                              const unsigned* __restrict__ W2F,
                                              const unsigned* __restrict__ W3F,
                                              float* __restrict__ S) {
    __shared__ float EDW[4][32][17];

    const int tid = threadIdx.x;
    const int wave = tid >> 6, lane = tid & 63;
    const int lrow = lane & 15, lgrp = lane >> 4;
    const int base_e = blockIdx.x * 128 + wave * 32;

    const int e0 = base_e + lrow;
    const int e1 = base_e + 16 + lrow;
    const int2 ij0 = ((const int2*)ud)[min(e0, NE - 1)];
    const int2 ij1 = ((const int2*)ud)[min(e1, NE - 1)];

    // be1 fragments (per ks)
    f32x4 b1a[2][2];
#pragma unroll
    for (int ks = 0; ks < 2; ks++) {
        b1a[ks][0] = *(const f32x4*)(be1 + ks * 32 + lgrp * 8);
        b1a[ks][1] = *(const f32x4*)(be1 + ks * 32 + lgrp * 8 + 4);
    }

    // U^T B-fragments: lane holds U[edge = nt*16+lrow][k = ks*32 + lgrp*8 + e]
    bf16x8 Uhi[2][2], Ulo[2][2];
#pragma unroll
    for (int nt = 0; nt < 2; nt++) {
        const int2 ij = nt ? ij1 : ij0;
        const float* gi = g + ij.x * 64;
        const float* gj = g + ij.y * 64;
#pragma unroll
        for (int ks = 0; ks < 2; ks++) {
            int kb = ks * 32 + lgrp * 8;
            f32x4 x0 = *(const f32x4*)(gi + kb);
            f32x4 x1 = *(const f32x4*)(gi + kb + 4);
            f32x4 y0 = *(const f32x4*)(gj + kb);
            f32x4 y1 = *(const f32x4*)(gj + kb + 4);
            float u[8];
#pragma unroll
            for (int e = 0; e < 4; e++) {
                u[e]     = lk(x0[e] + y0[e] + b1a[ks][0][e]);
                u[4 + e] = lk(x1[e] + y1[e] + b1a[ks][1][e]);
            }
            split8(u, Uhi[nt][ks], Ulo[nt][ks]);
        }
    }

    // layer 2: V^T = We2^T @ U^T (A = We2^T frags, B = U frags), then split to
    // bf16x4 which IS the 16x16x16 B-fragment for layer 3.
    bf16x4 Vhi[4][2], Vlo[4][2];
#pragma unroll
    for (int mt = 0; mt < 4; mt++) {
        f32x4 acc[2];
#pragma unroll
        for (int nt = 0; nt < 2; nt++)
#pragma unroll
            for (int q = 0; q < 4; q++) acc[nt][q] = 0.f;
#pragma unroll
        for (int ks = 0; ks < 2; ks++) {
            bf16x8 Whi = *(const bf16x8*)(W2F + ((mt * 2 + ks) * 2 + 0) * 256 + lane * 4);
            bf16x8 Wlo = *(const bf16x8*)(W2F + ((mt * 2 + ks) * 2 + 1) * 256 + lane * 4);
#pragma unroll
            for (int nt = 0; nt < 2; nt++) {
                acc[nt] = __builtin_amdgcn_mfma_f32_16x16x32_bf16(Whi, Uhi[nt][ks], acc[nt], 0, 0, 0);
                acc[nt] = __builtin_amdgcn_mfma_f32_16x16x32_bf16(Wlo, Uhi[nt][ks], acc[nt], 0, 0, 0);
                acc[nt] = __builtin_amdgcn_mfma_f32_16x16x32_bf16(Whi, Ulo[nt][ks], acc[nt], 0, 0, 0);
            }
        }
        f32x4 b2 = *(const f32x4*)(be2 + mt * 16 + lgrp * 4);
#pragma unroll
        for (int nt = 0; nt < 2; nt++) {
            float v[4];
#pragma unroll
            for (int q = 0; q < 4; q++) v[q] = lk(acc[nt][q] + b2[q]);
            split4(v, Vhi[mt][nt], Vlo[mt][nt]);
        }
    }

    // layer 3: ed^T = We3^T @ V^T (16x16x16, V frags straight from registers)
    f32x4 acc3[2];
#pragma unroll
    for (int nt = 0; nt < 2; nt++)
#pragma unroll
        for (int q = 0; q < 4; q++) acc3[nt][q] = 0.f;
#pragma unroll
    for (int kb = 0; kb < 4; kb++) {
        bf16x4 W3h = *(const bf16x4*)(W3F + (kb * 2 + 0) * 128 + lane * 2);
        bf16x4 W3l = *(const bf16x4*)(W3F + (kb * 2 + 1) * 128 + lane * 2);
#pragma unroll
        for (int nt = 0; nt < 2; nt++) {
            acc3[nt] = mfma1616(W3h, Vhi[kb][nt], acc3[nt]);
            acc3[nt] = mfma1616(W3l, Vhi[kb][nt], acc3[nt]);
            acc3[nt] = mfma1616(W3h, Vlo[kb][nt], acc3[nt]);
        }
    }

    // bias + upper-triangle stores (row a = lgrp of each edge's 4x4 block) + EDW stage
    f32x4 b3 = *(const f32x4*)(be3 + lgrp * 4);
#pragma unroll
    for (int nt = 0; nt < 2; nt++) {
        const int e = nt ? e1 : e0;
        const int2 ij = nt ? ij1 : ij0;
        float ed[4];
#pragma unroll
        for (int q = 0; q < 4; q++) {
            ed[q] = acc3[nt][q] + b3[q];
            EDW[wave][nt * 16 + lrow][lgrp * 4 + q] = ed[q];
        }
        if (e < NE) {
            *(float4*)&S[(4 * ij.x + lgrp) * SDIM + 4 * ij.y] =
                make_float4(ed[0], ed[1], ed[2], ed[3]);
        }
    }

    // lower-triangle (transposed) stores via per-wave LDS (wave-synchronous, no barrier)
    const int le = lane & 31;
    const int lg2 = lane >> 5;
    const int eL = base_e + le;
    const int2 ijL = ((const int2*)ud)[min(eL, NE - 1)];
#pragma unroll
    for (int q = 0; q < 2; q++) {
        int a = lg2 * 2 + q;
        float4 v = make_float4(EDW[wave][le][a], EDW[wave][le][4 + a],
                               EDW[wave][le][8 + a], EDW[wave][le][12 + a]);
        if (eL < NE) *(float4*)&S[(4 * ijL.y + a) * SDIM + 4 * ijL.x] = v;
    }
}

extern "C" void kernel_launch(void* const* d_in, const int* in_sizes, int n_in,
                              void* d_out, int out_size, void* d_ws, size_t ws_size,
                              hipStream_t stream) {
    const float* x   = (const float*)d_in[0];
    const int*   ud  = (const int*)d_in[3];
    const float* Wg1 = (const float*)d_in[4];
    const float* bg1 = (const float*)d_in[5];
    const float* Wg2 = (const float*)d_in[6];
    const float* bg2 = (const float*)d_in[7];
    const float* Wg3 = (const float*)d_in[8];
    const float* bg3 = (const float*)d_in[9];
    const float* Wn1 = (const float*)d_in[10];
    const float* bn1 = (const float*)d_in[11];
    const float* Wn2 = (const float*)d_in[12];
    const float* bn2 = (const float*)d_in[13];
    const float* Wn3 = (const float*)d_in[14];
    const float* bn3 = (const float*)d_in[15];
    const float* We1 = (const float*)d_in[16];
    const float* be1 = (const float*)d_in[17];
    const float* We2 = (const float*)d_in[18];
    const float* be2 = (const float*)d_in[19];
    const float* We3 = (const float*)d_in[20];
    const float* be3 = (const float*)d_in[21];

    float* out   = (float*)d_out;
    float* h_out = out;                 // 1200*64
    float* S     = out + 76800;         // 4800*4800

    float* ws  = (float*)d_ws;
    float* t1  = ws;                    // 38400
    float* t2  = ws + 38400;            // 38400
    float* t3  = ws + 76800;            // 76800
    float* g   = ws + 153600;           // 76800
    float* cs  = ws + 230400;           // 128
    unsigned* W2F = (unsigned*)(ws + 230528);  // 4096 u32
    unsigned* W3F = W2F + 4096;                // 1024 u32

    k_prep<<<4, 256, 0, stream>>>(We2, We3, W2F, W3F, cs);
    k_t1<<<38, 256, 0, stream>>>(x, Wg1, t1, cs);
    k_t2<<<38, 256, 0, stream>>>(t1, cs, bg1, Wg2, t2, cs + 32);
    k_t3<<<38, 256, 0, stream>>>(t2, cs + 32, bg2, Wg3, t3, cs + 64);
    k_g<<<38, 256, 0, stream>>>(t3, cs + 64, bg3, We1, h_out, g);
    k_edge<<<5621, 256, 0, stream>>>(ud, g, be1, be2, be3, W2F, W3F, S);
    k_vd<<<38, 256, 0, stream>>>(h_out, Wn1, bn1, Wn2, bn2, Wn3, bn3, S);
}